// Round 6
// baseline (898.209 us; speedup 1.0000x reference)
//
#include <hip/hip_runtime.h>
#include <hip/hip_bf16.h>

#define EPS_BN 1e-5f

constexpr int B  = 2048, F0 = 64, K = 14;
constexpr int C1 = 64,  F1 = 32;
constexpr int C2 = 128, F2 = 16;
constexpr int C3 = 256, F3 = 8;

typedef __attribute__((ext_vector_type(8))) short bf16x8;
typedef __attribute__((ext_vector_type(4))) float f32x4;

__device__ __forceinline__ float bf2f(unsigned short u) {
    union { unsigned int i; float f; } x; x.i = ((unsigned int)u) << 16; return x.f;
}
__device__ __forceinline__ unsigned short f2bf(float f) {
    union { float f; unsigned int i; } x; x.f = f;
    unsigned int r = (x.i + 0x7fffu + ((x.i >> 16) & 1u)) >> 16;
    return (unsigned short)r;
}

// DPP row_shl:1 (ctrl 0x101), zero-fill: dest lane m <- src lane m+1 (16-lane rows).
__device__ __forceinline__ bf16x8 dpp_shl1(bf16x8 v) {
    union { bf16x8 v; int i[4]; } a, r;
    a.v = v;
    #pragma unroll
    for (int j = 0; j < 4; ++j)
        r.i[j] = __builtin_amdgcn_update_dpp(0, a.i[j], 0x101, 0xf, 0xf, true);
    return r.v;
}

// ---- fold BN into conv1 weights ----
__global__ void repack_w1(const float* __restrict__ w1, const float* __restrict__ g,
                          const float* __restrict__ bb, const float* __restrict__ m,
                          const float* __restrict__ v, float* __restrict__ w1f,
                          float* __restrict__ t1) {
    int i = blockIdx.x * 256 + threadIdx.x;
    if (i < C1) {
        float s = g[i] * rsqrtf(v[i] + EPS_BN);
        t1[i] = bb[i] - m[i] * s;
    }
    if (i < C1 * 2 * 9) {
        int c = i / 18;
        float s = g[c] * rsqrtf(v[c] + EPS_BN);
        w1f[i] = w1[i] * s;
    }
}

// ---- repack conv weights into MFMA B-fragment layout, bf16, BN-folded ----
template<int CIN, int COUT>
__global__ void repack_mfma(const float* __restrict__ w, const float* __restrict__ g,
                            const float* __restrict__ bb, const float* __restrict__ m,
                            const float* __restrict__ v, unsigned short* __restrict__ wp,
                            float* __restrict__ t) {
    int idx = blockIdx.x * 256 + threadIdx.x;
    if (idx < COUT) {
        float s = g[idx] * rsqrtf(v[idx] + EPS_BN);
        t[idx] = bb[idx] - m[idx] * s;
    }
    if (idx < 9 * CIN * COUT) {
        constexpr int CCS = CIN / 32;
        int kk = idx & 31;
        int rest = idx >> 5;
        int n = rest & (COUT - 1);
        int chunk = rest / COUT;
        int tap = chunk / CCS;
        int cc  = chunk & (CCS - 1);
        int ci = cc * 32 + kk;
        float s = g[n] * rsqrtf(v[n] + EPS_BN);
        wp[idx] = f2bf(w[(n * CIN + ci) * 9 + tap] * s);
    }
}

__global__ void zero_out(float* __restrict__ out) {
    int i = blockIdx.x * 256 + threadIdx.x;
    if (i < B * K * 2) out[i] = 0.f;
}

// ---- fully fused conv1+conv2+conv3+conv4 ----
// Block (h, b): 512 threads / 8 waves; h selects output half (conv3 rows 4h..4h+3).
// Per-wave tiles halved vs r5 to kill scratch spills: conv2 NT=1, conv3 NT=2.
__launch_bounds__(512, 4)
__global__ void fused_all(const float* __restrict__ x, const float* __restrict__ sig,
                          const float* __restrict__ w1f, const float* __restrict__ t1,
                          const unsigned short* __restrict__ wp2, const float* __restrict__ t2,
                          const unsigned short* __restrict__ wp3, const float* __restrict__ t3,
                          const float* __restrict__ w4, float* __restrict__ out) {
    __shared__ alignas(16) unsigned short s2l[19 * 16 * 64];   // conv1 out (rotated slots)
    __shared__ alignas(16) unsigned short s3l[9 * 16 * 128];   // conv2 out (rotated); x/sig overlay
    __shared__ float red[8][4][4][2];

    const int h = blockIdx.x, b = blockIdx.y, t = threadIdx.x;
    const int lane = t & 63, wave = t >> 6;
    const int m = lane & 15, q = lane >> 4;

    // ph0: zero s2, stage x/sig (overlaid on s3)
    float* xs = (float*)s3l;
    float* ss = xs + F0 * K;
    for (int i = t; i < 19 * 16 * 64 / 8; i += 512) ((uint4*)s2l)[i] = uint4{0, 0, 0, 0};
    for (int i = t; i < F0 * K; i += 512) {
        xs[i] = x[(size_t)b * F0 * K + i];
        ss[i] = sig[(size_t)b * F0 * K + i] * 10.0f;
    }
    __syncthreads();

    // ph1: conv1 -> s2 (planes f1 = 16h-3 .. 16h+15)
    {
        const int c1 = t & 63;
        float wx[9], wg[9];
        #pragma unroll
        for (int r = 0; r < 9; ++r) { wx[r] = w1f[c1 * 18 + r]; wg[r] = w1f[c1 * 18 + 9 + r]; }
        const float bias = t1[c1];
        for (int pos = wave; pos < 19 * 14; pos += 8) {
            int pi = pos / 14, k = pos % 14;
            int f1 = pi + 16 * h - 3;
            if (f1 < 0 || f1 >= F1) continue;
            float acc = bias;
            #pragma unroll
            for (int df = 0; df < 3; ++df) {
                int fi = 2 * f1 + df - 1;
                if (fi < 0 || fi >= F0) continue;
                #pragma unroll
                for (int dk = 0; dk < 3; ++dk) {
                    int ki = k + dk - 1;
                    if (ki < 0 || ki >= K) continue;
                    acc = fmaf(xs[fi * K + ki], wx[df * 3 + dk], acc);
                    acc = fmaf(ss[fi * K + ki], wg[df * 3 + dk], acc);
                }
            }
            int p = k + 1;
            s2l[(pi * 16 + p) * 64 + (((c1 >> 3) + p) & 7) * 8 + (c1 & 7)] = f2bf(fmaxf(acc, 0.f));
        }
    }
    __syncthreads();

    // ph1b: zero s3 (kills x/sig overlay; provides pad slots + invalid-row zeros)
    for (int i = t; i < 9 * 16 * 128 / 8; i += 512) ((uint4*)s3l)[i] = uint4{0, 0, 0, 0};
    __syncthreads();

    // ph2: conv2 MFMA (9 h2 rows r = 8h-1 .. 8h+7) -> s3 ; wave owns 16 cols (NT=1)
    {
        const int nb = wave * 16;
        f32x4 acc2[9];
        {
            float bz = t2[nb + m];
            #pragma unroll
            for (int rr = 0; rr < 9; ++rr) acc2[rr] = f32x4{bz, bz, bz, bz};
        }
        #pragma unroll
        for (int df = 0; df < 3; ++df)
        #pragma unroll
        for (int cc = 0; cc < 2; ++cc) {
            bf16x8 bv[3];
            #pragma unroll
            for (int dk = 0; dk < 3; ++dk) {
                int chunk = (df * 3 + dk) * 2 + cc;
                bv[dk] = *(const bf16x8*)(wp2 + ((chunk * C2 + nb + m) << 5) + q * 8);
            }
            #pragma unroll
            for (int rr = 0; rr < 9; ++rr) {
                const unsigned short* ap = s2l + ((2 * rr + df) * 16 + m) * 64 + ((cc * 4 + q + m) & 7) * 8;
                bf16x8 a0 = *(const bf16x8*)ap;
                bf16x8 a1 = dpp_shl1(a0);
                bf16x8 a2 = dpp_shl1(a1);
                acc2[rr] = __builtin_amdgcn_mfma_f32_16x16x32_bf16(a0, bv[0], acc2[rr], 0, 0, 0);
                acc2[rr] = __builtin_amdgcn_mfma_f32_16x16x32_bf16(a1, bv[1], acc2[rr], 0, 0, 0);
                acc2[rr] = __builtin_amdgcn_mfma_f32_16x16x32_bf16(a2, bv[2], acc2[rr], 0, 0, 0);
            }
        }
        #pragma unroll
        for (int rr = 0; rr < 9; ++rr) {
            int r = rr + 8 * h - 1;
            if (r < 0 || r >= F2) continue;       // invalid rows stay zero
            int ch = nb + m;
            int c = ch >> 3, sub = ch & 7;
            #pragma unroll
            for (int i = 0; i < 4; ++i) {
                int kp = q * 4 + i;
                if (kp >= K) continue;
                int p = kp + 1;
                s3l[(rr * 16 + p) * 128 + ((c + p) & 15) * 8 + sub] = f2bf(fmaxf(acc2[rr][i], 0.f));
            }
        }
    }
    __syncthreads();

    // ph3: conv3 MFMA (rows f3 = 4h+g), wave owns 32 cols (NT=2); ph4: conv4 on accs
    {
        const int nb = wave * 32;
        f32x4 acc3[4][2];
        #pragma unroll
        for (int nt = 0; nt < 2; ++nt) {
            float bz = t3[nb + nt * 16 + m];
            #pragma unroll
            for (int g = 0; g < 4; ++g) acc3[g][nt] = f32x4{bz, bz, bz, bz};
        }
        #pragma unroll
        for (int df = 0; df < 3; ++df)
        #pragma unroll
        for (int cc = 0; cc < 4; ++cc) {
            bf16x8 bv[3][2];
            #pragma unroll
            for (int dk = 0; dk < 3; ++dk) {
                int chunk = (df * 3 + dk) * 4 + cc;
                #pragma unroll
                for (int nt = 0; nt < 2; ++nt)
                    bv[dk][nt] = *(const bf16x8*)(wp3 + ((chunk * C3 + nb + nt * 16 + m) << 5) + q * 8);
            }
            #pragma unroll
            for (int g = 0; g < 4; ++g) {
                const unsigned short* ap = s3l + ((2 * g + df) * 16 + m) * 128 + ((cc * 4 + q + m) & 15) * 8;
                bf16x8 a0 = *(const bf16x8*)ap;
                bf16x8 a1 = dpp_shl1(a0);
                bf16x8 a2 = dpp_shl1(a1);
                #pragma unroll
                for (int nt = 0; nt < 2; ++nt)
                    acc3[g][nt] = __builtin_amdgcn_mfma_f32_16x16x32_bf16(a0, bv[0][nt], acc3[g][nt], 0, 0, 0);
                #pragma unroll
                for (int nt = 0; nt < 2; ++nt)
                    acc3[g][nt] = __builtin_amdgcn_mfma_f32_16x16x32_bf16(a1, bv[1][nt], acc3[g][nt], 0, 0, 0);
                #pragma unroll
                for (int nt = 0; nt < 2; ++nt)
                    acc3[g][nt] = __builtin_amdgcn_mfma_f32_16x16x32_bf16(a2, bv[2][nt], acc3[g][nt], 0, 0, 0);
            }
        }
        // ph4: conv4 partials (ReLU + dot over (ch, f3) owned by this lane)
        float so[2][4] = {{0.f, 0.f, 0.f, 0.f}, {0.f, 0.f, 0.f, 0.f}};
        #pragma unroll
        for (int nt = 0; nt < 2; ++nt) {
            int ch = nb + nt * 16 + m;
            #pragma unroll
            for (int g = 0; g < 4; ++g) {
                int f3 = 4 * h + g;
                float wa = w4[(0 * C3 + ch) * 8 + f3];
                float wb = w4[(1 * C3 + ch) * 8 + f3];
                #pragma unroll
                for (int i = 0; i < 4; ++i) {
                    float vv = fmaxf(acc3[g][nt][i], 0.f);
                    so[0][i] = fmaf(vv, wa, so[0][i]);
                    so[1][i] = fmaf(vv, wb, so[1][i]);
                }
            }
        }
        #pragma unroll
        for (int off = 1; off < 16; off <<= 1)
            #pragma unroll
            for (int o = 0; o < 2; ++o)
                #pragma unroll
                for (int i = 0; i < 4; ++i)
                    so[o][i] += __shfl_xor(so[o][i], off, 64);
        if (m == 0) {
            #pragma unroll
            for (int i = 0; i < 4; ++i) {
                red[wave][q][i][0] = so[0][i];
                red[wave][q][i][1] = so[1][i];
            }
        }
    }
    __syncthreads();
    if (t < K * 2) {
        int k = t >> 1, o = t & 1;
        float v = 0.f;
        #pragma unroll
        for (int w = 0; w < 8; ++w) v += red[w][k >> 2][k & 3][o];
        atomicAdd(&out[(b * K + k) * 2 + o], v);
    }
}

extern "C" void kernel_launch(void* const* d_in, const int* in_sizes, int n_in,
                              void* d_out, int out_size, void* d_ws, size_t ws_size,
                              hipStream_t stream) {
    const float* x   = (const float*)d_in[0];
    const float* sig = (const float*)d_in[1];
    const float* w1  = (const float*)d_in[2];
    const float* w2  = (const float*)d_in[3];
    const float* w3  = (const float*)d_in[4];
    const float* w4  = (const float*)d_in[5];
    const float* g1  = (const float*)d_in[6];
    const float* b1  = (const float*)d_in[7];
    const float* m1  = (const float*)d_in[8];
    const float* v1  = (const float*)d_in[9];
    const float* g2  = (const float*)d_in[10];
    const float* b2  = (const float*)d_in[11];
    const float* m2  = (const float*)d_in[12];
    const float* v2  = (const float*)d_in[13];
    const float* g3  = (const float*)d_in[14];
    const float* b3  = (const float*)d_in[15];
    const float* m3  = (const float*)d_in[16];
    const float* v3  = (const float*)d_in[17];

    char* ws = (char*)d_ws;
    size_t off = 0;
    auto alloc = [&](size_t bytes) {
        char* p = ws + off;
        off += (bytes + 255) & ~(size_t)255;
        return p;
    };
    float* w1f = (float*)alloc((size_t)C1 * 2 * 9 * 4);
    float* t1  = (float*)alloc((size_t)C1 * 4);
    unsigned short* wp2 = (unsigned short*)alloc((size_t)9 * C1 * C2 * 2);
    float* t2  = (float*)alloc((size_t)C2 * 4);
    unsigned short* wp3 = (unsigned short*)alloc((size_t)9 * C2 * C3 * 2);
    float* t3  = (float*)alloc((size_t)C3 * 4);

    repack_w1<<<(C1 * 2 * 9 + 255) / 256, 256, 0, stream>>>(w1, g1, b1, m1, v1, w1f, t1);
    repack_mfma<C1, C2><<<(9 * C1 * C2 + 255) / 256, 256, 0, stream>>>(w2, g2, b2, m2, v2, wp2, t2);
    repack_mfma<C2, C3><<<(9 * C2 * C3 + 255) / 256, 256, 0, stream>>>(w3, g3, b3, m3, v3, wp3, t3);
    zero_out<<<(B * K * 2 + 255) / 256, 256, 0, stream>>>((float*)d_out);

    fused_all<<<dim3(2, B), 512, 0, stream>>>(x, sig, w1f, t1, wp2, t2, wp3, t3, w4, (float*)d_out);
}

// Round 7
// 635.699 us; speedup vs baseline: 1.4129x; 1.4129x over previous
//
#include <hip/hip_runtime.h>
#include <hip/hip_bf16.h>

#define EPS_BN 1e-5f

constexpr int B  = 2048, F0 = 64, K = 14;
constexpr int C1 = 64,  F1 = 32;
constexpr int C2 = 128, F2 = 16;
constexpr int C3 = 256, F3 = 8;

typedef __attribute__((ext_vector_type(8))) short bf16x8;
typedef __attribute__((ext_vector_type(4))) float f32x4;

__device__ __forceinline__ float bf2f(unsigned short u) {
    union { unsigned int i; float f; } x; x.i = ((unsigned int)u) << 16; return x.f;
}
__device__ __forceinline__ unsigned short f2bf(float f) {
    union { float f; unsigned int i; } x; x.f = f;
    unsigned int r = (x.i + 0x7fffu + ((x.i >> 16) & 1u)) >> 16;
    return (unsigned short)r;
}

// DPP row_shl:1 (ctrl 0x101), zero-fill: dest lane m <- src lane m+1 (16-lane rows).
__device__ __forceinline__ bf16x8 dpp_shl1(bf16x8 v) {
    union { bf16x8 v; int i[4]; } a, r;
    a.v = v;
    #pragma unroll
    for (int j = 0; j < 4; ++j)
        r.i[j] = __builtin_amdgcn_update_dpp(0, a.i[j], 0x101, 0xf, 0xf, true);
    return r.v;
}

// ---- fold BN into conv1 weights ----
__global__ void repack_w1(const float* __restrict__ w1, const float* __restrict__ g,
                          const float* __restrict__ bb, const float* __restrict__ m,
                          const float* __restrict__ v, float* __restrict__ w1f,
                          float* __restrict__ t1) {
    int i = blockIdx.x * 256 + threadIdx.x;
    if (i < C1) {
        float s = g[i] * rsqrtf(v[i] + EPS_BN);
        t1[i] = bb[i] - m[i] * s;
    }
    if (i < C1 * 2 * 9) {
        int c = i / 18;
        float s = g[c] * rsqrtf(v[c] + EPS_BN);
        w1f[i] = w1[i] * s;
    }
}

// ---- repack conv weights into MFMA B-fragment layout, bf16, BN-folded ----
template<int CIN, int COUT>
__global__ void repack_mfma(const float* __restrict__ w, const float* __restrict__ g,
                            const float* __restrict__ bb, const float* __restrict__ m,
                            const float* __restrict__ v, unsigned short* __restrict__ wp,
                            float* __restrict__ t) {
    int idx = blockIdx.x * 256 + threadIdx.x;
    if (idx < COUT) {
        float s = g[idx] * rsqrtf(v[idx] + EPS_BN);
        t[idx] = bb[idx] - m[idx] * s;
    }
    if (idx < 9 * CIN * COUT) {
        constexpr int CCS = CIN / 32;
        int kk = idx & 31;
        int rest = idx >> 5;
        int n = rest & (COUT - 1);
        int chunk = rest / COUT;
        int tap = chunk / CCS;
        int cc  = chunk & (CCS - 1);
        int ci = cc * 32 + kk;
        float s = g[n] * rsqrtf(v[n] + EPS_BN);
        wp[idx] = f2bf(w[(n * CIN + ci) * 9 + tap] * s);
    }
}

__global__ void zero_out(float* __restrict__ out) {
    int i = blockIdx.x * 256 + threadIdx.x;
    if (i < B * K * 2) out[i] = 0.f;
}

// ---- fully fused conv1+conv2+conv3+conv4 ----
// Block (h, b): 512 threads / 8 waves; h selects output half (conv3 rows 4h..4h+3).
// NOTE __launch_bounds__ 2nd arg behaves as min BLOCKS/CU on this toolchain
// (evidence: (256,2)->128 VGPR cap, (512,4)->64 VGPR cap => cap = 512/(blocks*waves_per_simd)).
// (512,2): cap 128 VGPR, 2 blocks/CU — matches the 76.8 KB LDS limit, no spills.
__launch_bounds__(512, 2)
__global__ void fused_all(const float* __restrict__ x, const float* __restrict__ sig,
                          const float* __restrict__ w1f, const float* __restrict__ t1,
                          const unsigned short* __restrict__ wp2, const float* __restrict__ t2,
                          const unsigned short* __restrict__ wp3, const float* __restrict__ t3,
                          const float* __restrict__ w4, float* __restrict__ out) {
    __shared__ alignas(16) unsigned short s2l[19 * 16 * 64];   // conv1 out (rotated slots)
    __shared__ alignas(16) unsigned short s3l[9 * 16 * 128];   // conv2 out (rotated); x/sig overlay
    __shared__ float red[8][4][4][2];

    const int h = blockIdx.x, b = blockIdx.y, t = threadIdx.x;
    const int lane = t & 63, wave = t >> 6;
    const int m = lane & 15, q = lane >> 4;

    // ph0: zero s2, stage x/sig (overlaid on s3)
    float* xs = (float*)s3l;
    float* ss = xs + F0 * K;
    for (int i = t; i < 19 * 16 * 64 / 8; i += 512) ((uint4*)s2l)[i] = uint4{0, 0, 0, 0};
    for (int i = t; i < F0 * K; i += 512) {
        xs[i] = x[(size_t)b * F0 * K + i];
        ss[i] = sig[(size_t)b * F0 * K + i] * 10.0f;
    }
    __syncthreads();

    // ph1: conv1 -> s2 (planes f1 = 16h-3 .. 16h+15)
    {
        const int c1 = t & 63;
        float wx[9], wg[9];
        #pragma unroll
        for (int r = 0; r < 9; ++r) { wx[r] = w1f[c1 * 18 + r]; wg[r] = w1f[c1 * 18 + 9 + r]; }
        const float bias = t1[c1];
        for (int pos = wave; pos < 19 * 14; pos += 8) {
            int pi = pos / 14, k = pos % 14;
            int f1 = pi + 16 * h - 3;
            if (f1 < 0 || f1 >= F1) continue;
            float acc = bias;
            #pragma unroll
            for (int df = 0; df < 3; ++df) {
                int fi = 2 * f1 + df - 1;
                if (fi < 0 || fi >= F0) continue;
                #pragma unroll
                for (int dk = 0; dk < 3; ++dk) {
                    int ki = k + dk - 1;
                    if (ki < 0 || ki >= K) continue;
                    acc = fmaf(xs[fi * K + ki], wx[df * 3 + dk], acc);
                    acc = fmaf(ss[fi * K + ki], wg[df * 3 + dk], acc);
                }
            }
            int p = k + 1;
            s2l[(pi * 16 + p) * 64 + (((c1 >> 3) + p) & 7) * 8 + (c1 & 7)] = f2bf(fmaxf(acc, 0.f));
        }
    }
    __syncthreads();

    // ph1b: zero s3 (kills x/sig overlay; provides pad slots + invalid-row zeros)
    for (int i = t; i < 9 * 16 * 128 / 8; i += 512) ((uint4*)s3l)[i] = uint4{0, 0, 0, 0};
    __syncthreads();

    // ph2: conv2 MFMA (9 h2 rows r = 8h-1 .. 8h+7) -> s3 ; wave owns 16 cols (NT=1)
    {
        const int nb = wave * 16;
        f32x4 acc2[9];
        {
            float bz = t2[nb + m];
            #pragma unroll
            for (int rr = 0; rr < 9; ++rr) acc2[rr] = f32x4{bz, bz, bz, bz};
        }
        #pragma unroll
        for (int df = 0; df < 3; ++df)
        #pragma unroll
        for (int cc = 0; cc < 2; ++cc) {
            bf16x8 bv[3];
            #pragma unroll
            for (int dk = 0; dk < 3; ++dk) {
                int chunk = (df * 3 + dk) * 2 + cc;
                bv[dk] = *(const bf16x8*)(wp2 + ((chunk * C2 + nb + m) << 5) + q * 8);
            }
            #pragma unroll
            for (int rr = 0; rr < 9; ++rr) {
                const unsigned short* ap = s2l + ((2 * rr + df) * 16 + m) * 64 + ((cc * 4 + q + m) & 7) * 8;
                bf16x8 a0 = *(const bf16x8*)ap;
                bf16x8 a1 = dpp_shl1(a0);
                bf16x8 a2 = dpp_shl1(a1);
                acc2[rr] = __builtin_amdgcn_mfma_f32_16x16x32_bf16(a0, bv[0], acc2[rr], 0, 0, 0);
                acc2[rr] = __builtin_amdgcn_mfma_f32_16x16x32_bf16(a1, bv[1], acc2[rr], 0, 0, 0);
                acc2[rr] = __builtin_amdgcn_mfma_f32_16x16x32_bf16(a2, bv[2], acc2[rr], 0, 0, 0);
            }
        }
        #pragma unroll
        for (int rr = 0; rr < 9; ++rr) {
            int r = rr + 8 * h - 1;
            if (r < 0 || r >= F2) continue;       // invalid rows stay zero
            int ch = nb + m;
            int c = ch >> 3, sub = ch & 7;
            #pragma unroll
            for (int i = 0; i < 4; ++i) {
                int kp = q * 4 + i;
                if (kp >= K) continue;
                int p = kp + 1;
                s3l[(rr * 16 + p) * 128 + ((c + p) & 15) * 8 + sub] = f2bf(fmaxf(acc2[rr][i], 0.f));
            }
        }
    }
    __syncthreads();

    // ph3: conv3 MFMA (rows f3 = 4h+g), wave owns 32 cols (NT=2); ph4: conv4 on accs
    {
        const int nb = wave * 32;
        f32x4 acc3[4][2];
        #pragma unroll
        for (int nt = 0; nt < 2; ++nt) {
            float bz = t3[nb + nt * 16 + m];
            #pragma unroll
            for (int g = 0; g < 4; ++g) acc3[g][nt] = f32x4{bz, bz, bz, bz};
        }
        #pragma unroll
        for (int df = 0; df < 3; ++df)
        #pragma unroll
        for (int cc = 0; cc < 4; ++cc) {
            bf16x8 bv[3][2];
            #pragma unroll
            for (int dk = 0; dk < 3; ++dk) {
                int chunk = (df * 3 + dk) * 4 + cc;
                #pragma unroll
                for (int nt = 0; nt < 2; ++nt)
                    bv[dk][nt] = *(const bf16x8*)(wp3 + ((chunk * C3 + nb + nt * 16 + m) << 5) + q * 8);
            }
            #pragma unroll
            for (int g = 0; g < 4; ++g) {
                const unsigned short* ap = s3l + ((2 * g + df) * 16 + m) * 128 + ((cc * 4 + q + m) & 15) * 8;
                bf16x8 a0 = *(const bf16x8*)ap;
                bf16x8 a1 = dpp_shl1(a0);
                bf16x8 a2 = dpp_shl1(a1);
                #pragma unroll
                for (int nt = 0; nt < 2; ++nt)
                    acc3[g][nt] = __builtin_amdgcn_mfma_f32_16x16x32_bf16(a0, bv[0][nt], acc3[g][nt], 0, 0, 0);
                #pragma unroll
                for (int nt = 0; nt < 2; ++nt)
                    acc3[g][nt] = __builtin_amdgcn_mfma_f32_16x16x32_bf16(a1, bv[1][nt], acc3[g][nt], 0, 0, 0);
                #pragma unroll
                for (int nt = 0; nt < 2; ++nt)
                    acc3[g][nt] = __builtin_amdgcn_mfma_f32_16x16x32_bf16(a2, bv[2][nt], acc3[g][nt], 0, 0, 0);
            }
        }
        // ph4: conv4 partials (ReLU + dot over (ch, f3) owned by this lane)
        float so[2][4] = {{0.f, 0.f, 0.f, 0.f}, {0.f, 0.f, 0.f, 0.f}};
        #pragma unroll
        for (int nt = 0; nt < 2; ++nt) {
            int ch = nb + nt * 16 + m;
            #pragma unroll
            for (int g = 0; g < 4; ++g) {
                int f3 = 4 * h + g;
                float wa = w4[(0 * C3 + ch) * 8 + f3];
                float wb = w4[(1 * C3 + ch) * 8 + f3];
                #pragma unroll
                for (int i = 0; i < 4; ++i) {
                    float vv = fmaxf(acc3[g][nt][i], 0.f);
                    so[0][i] = fmaf(vv, wa, so[0][i]);
                    so[1][i] = fmaf(vv, wb, so[1][i]);
                }
            }
        }
        #pragma unroll
        for (int off = 1; off < 16; off <<= 1)
            #pragma unroll
            for (int o = 0; o < 2; ++o)
                #pragma unroll
                for (int i = 0; i < 4; ++i)
                    so[o][i] += __shfl_xor(so[o][i], off, 64);
        if (m == 0) {
            #pragma unroll
            for (int i = 0; i < 4; ++i) {
                red[wave][q][i][0] = so[0][i];
                red[wave][q][i][1] = so[1][i];
            }
        }
    }
    __syncthreads();
    if (t < K * 2) {
        int k = t >> 1, o = t & 1;
        float v = 0.f;
        #pragma unroll
        for (int w = 0; w < 8; ++w) v += red[w][k >> 2][k & 3][o];
        atomicAdd(&out[(b * K + k) * 2 + o], v);
    }
}

extern "C" void kernel_launch(void* const* d_in, const int* in_sizes, int n_in,
                              void* d_out, int out_size, void* d_ws, size_t ws_size,
                              hipStream_t stream) {
    const float* x   = (const float*)d_in[0];
    const float* sig = (const float*)d_in[1];
    const float* w1  = (const float*)d_in[2];
    const float* w2  = (const float*)d_in[3];
    const float* w3  = (const float*)d_in[4];
    const float* w4  = (const float*)d_in[5];
    const float* g1  = (const float*)d_in[6];
    const float* b1  = (const float*)d_in[7];
    const float* m1  = (const float*)d_in[8];
    const float* v1  = (const float*)d_in[9];
    const float* g2  = (const float*)d_in[10];
    const float* b2  = (const float*)d_in[11];
    const float* m2  = (const float*)d_in[12];
    const float* v2  = (const float*)d_in[13];
    const float* g3  = (const float*)d_in[14];
    const float* b3  = (const float*)d_in[15];
    const float* m3  = (const float*)d_in[16];
    const float* v3  = (const float*)d_in[17];

    char* ws = (char*)d_ws;
    size_t off = 0;
    auto alloc = [&](size_t bytes) {
        char* p = ws + off;
        off += (bytes + 255) & ~(size_t)255;
        return p;
    };
    float* w1f = (float*)alloc((size_t)C1 * 2 * 9 * 4);
    float* t1  = (float*)alloc((size_t)C1 * 4);
    unsigned short* wp2 = (unsigned short*)alloc((size_t)9 * C1 * C2 * 2);
    float* t2  = (float*)alloc((size_t)C2 * 4);
    unsigned short* wp3 = (unsigned short*)alloc((size_t)9 * C2 * C3 * 2);
    float* t3  = (float*)alloc((size_t)C3 * 4);

    repack_w1<<<(C1 * 2 * 9 + 255) / 256, 256, 0, stream>>>(w1, g1, b1, m1, v1, w1f, t1);
    repack_mfma<C1, C2><<<(9 * C1 * C2 + 255) / 256, 256, 0, stream>>>(w2, g2, b2, m2, v2, wp2, t2);
    repack_mfma<C2, C3><<<(9 * C2 * C3 + 255) / 256, 256, 0, stream>>>(w3, g3, b3, m3, v3, wp3, t3);
    zero_out<<<(B * K * 2 + 255) / 256, 256, 0, stream>>>((float*)d_out);

    fused_all<<<dim3(2, B), 512, 0, stream>>>(x, sig, w1f, t1, wp2, t2, wp3, t3, w4, (float*)d_out);
}